// Round 9
// baseline (531.303 us; speedup 1.0000x reference)
//
#include <hip/hip_runtime.h>
#include <hip/hip_bf16.h>

#define B_ 256
#define T_ 512
#define I_ 128
#define H_ 256

typedef __bf16 bf16x8 __attribute__((ext_vector_type(8)));
typedef float  f32x4  __attribute__((ext_vector_type(4)));
typedef unsigned short u16;
typedef unsigned int   u32;

union U16x8Cast { uint4 v; bf16x8 b; };

__device__ inline u16 f2b(float f) {           // fp32 -> bf16 bits (RNE)
    union { __bf16 h; u16 u; } c; c.h = (__bf16)f; return c.u;
}
__device__ inline bf16x8 pack8(float4 lo, float4 hi) {
    bf16x8 f;
    f[0]=(__bf16)lo.x; f[1]=(__bf16)lo.y; f[2]=(__bf16)lo.z; f[3]=(__bf16)lo.w;
    f[4]=(__bf16)hi.x; f[5]=(__bf16)hi.y; f[6]=(__bf16)hi.z; f[7]=(__bf16)hi.w;
    return f;
}
__device__ inline uint2 pack4(float a, float b, float c, float d) {
    uint2 p;
    p.x = (u32)f2b(a) | ((u32)f2b(b) << 16);
    p.y = (u32)f2b(c) | ((u32)f2b(d) << 16);
    return p;
}
__device__ inline f32x4 b4_to_f32x4(uint2 u) {
    f32x4 r;
    r[0] = __uint_as_float(u.x << 16);
    r[1] = __uint_as_float(u.x & 0xFFFF0000u);
    r[2] = __uint_as_float(u.y << 16);
    r[3] = __uint_as_float(u.y & 0xFFFF0000u);
    return r;
}
// tanh(x) = 1 - 2/(1+e^{2x}); v_rcp (±1 ulp) beats the precise-div sequence.
__device__ inline float fast_tanh(float x) {
    float e = __expf(2.f * x);
    float d = 1.f + e;
    float r;
    asm("v_rcp_f32 %0, %1" : "=v"(r) : "v"(d));
    return fmaf(-2.f, r, 1.f);
}

// LDS-drain-only workgroup barrier: no vmcnt drain -> global prefetches
// stay in flight across the barrier (proven win, R8: -46% scan time).
#define WG_BARRIER() asm volatile("s_waitcnt lgkmcnt(0)\n\ts_barrier" ::: "memory")

// =====================================================================
// Kernel 1 (MFMA GEMM, unchanged from R8/R5): xw[t][b][n]
// =====================================================================
#define LDST 264
__global__ __launch_bounds__(256, 2) void xw_gemm_mfma(const float* __restrict__ x,
                                                       const float* __restrict__ W_ih,
                                                       const float* __restrict__ b_ih,
                                                       const float* __restrict__ b_hh,
                                                       u16* __restrict__ xw) {
    __shared__ u16 tile[64 * LDST];

    const int tid  = (int)threadIdx.x;
    const int wave = tid >> 6;
    const int lane = tid & 63;
    const int q    = lane >> 4;
    const int ml   = lane & 15;
    const int m0   = (int)blockIdx.x * 128;
    const int b    = m0 >> 9;
    const int t0   = m0 & 511;
    const int n0   = wave * 64;

    bf16x8 wA[4][4];
#pragma unroll
    for (int tau = 0; tau < 4; ++tau) {
        const float* wr = W_ih + (size_t)(n0 + tau * 16 + ml) * I_;
#pragma unroll
        for (int kap = 0; kap < 4; ++kap) {
            const int k0 = kap * 32 + q * 8;
            wA[tau][kap] = pack8(*(const float4*)(wr + k0), *(const float4*)(wr + k0 + 4));
        }
    }

    f32x4 acc[8][4];
#pragma unroll
    for (int mt = 0; mt < 8; ++mt)
#pragma unroll
        for (int tau = 0; tau < 4; ++tau) acc[mt][tau] = (f32x4)0.f;

#pragma unroll
    for (int kap = 0; kap < 4; ++kap) {
        bf16x8 xB[8];
#pragma unroll
        for (int mt = 0; mt < 8; ++mt) {
            const float* xr = x + (size_t)(m0 + mt * 16 + ml) * I_ + kap * 32 + q * 8;
            xB[mt] = pack8(*(const float4*)xr, *(const float4*)(xr + 4));
        }
#pragma unroll
        for (int mt = 0; mt < 8; ++mt)
#pragma unroll
            for (int tau = 0; tau < 4; ++tau)
                acc[mt][tau] = __builtin_amdgcn_mfma_f32_16x16x32_bf16(
                    wA[tau][kap], xB[mt], acc[mt][tau], 0, 0, 0);
    }

    float4 bias4[4];
#pragma unroll
    for (int tau = 0; tau < 4; ++tau) {
        const int n = n0 + tau * 16 + q * 4;
        float4 bi = *(const float4*)(b_ih + n);
        float4 bh = *(const float4*)(b_hh + n);
        bias4[tau] = make_float4(bi.x + bh.x, bi.y + bh.y, bi.z + bh.z, bi.w + bh.w);
    }

#pragma unroll
    for (int p = 0; p < 2; ++p) {
        if (p) __syncthreads();
#pragma unroll
        for (int mt = 0; mt < 4; ++mt) {
            const int row = mt * 16 + ml;
            const int mg  = p * 4 + mt;
#pragma unroll
            for (int tau = 0; tau < 4; ++tau) {
                uint2 pk = pack4(acc[mg][tau][0] + bias4[tau].x,
                                 acc[mg][tau][1] + bias4[tau].y,
                                 acc[mg][tau][2] + bias4[tau].z,
                                 acc[mg][tau][3] + bias4[tau].w);
                *(uint2*)(tile + row * LDST + n0 + tau * 16 + q * 4) = pk;
            }
        }
        __syncthreads();
#pragma unroll
        for (int s = 0; s < 4; ++s) {
            const int rr = s * 16 + (tid >> 4);
            const int c  = tid & 15;
            const uint4* srcp = (const uint4*)(tile + rr * LDST);
            uint4* dstp = (uint4*)(xw + ((size_t)(t0 + p * 64 + rr) * B_ + b) * H_);
            uint4 v0 = srcp[c];
            uint4 v1 = srcp[c + 16];
            dstp[c] = v0;
            dstp[c + 16] = v1;
        }
    }
}

// =====================================================================
// Kernel 2 (MFMA scan) — R8 structure with FAT WAVES: 16 WGs x 256 thr,
// 4 waves x 64 n-rows each (1 wave/SIMD). vs R8 (8 waves x 32 rows):
//   DS reads per CU per step: 64 -> 32 ds_read_b128 (the modeled floor)
//   MFMA ILP per wave: 2 -> 4 independent chains (hides dep latency at
//   1/SIMD). Keeps R8's proven pfA/pfB 2-step prefetch + lgkm-only
//   barrier + v_rcp tanh. This is R5's shape minus R5's two fatal bugs.
// =====================================================================
__global__ __launch_bounds__(256, 1) void rnn_scan_mfma(const u16* __restrict__ xw,
                                                        const float* __restrict__ W_hh,
                                                        const float* __restrict__ fc_w,
                                                        const float* __restrict__ fc_b,
                                                        float* __restrict__ out) {
    __shared__ __attribute__((aligned(16))) u16 hbuf[2][4096];  // 2 x 8 KB
    __shared__ float red[4][16];

    const int tid  = (int)threadIdx.x;
    const int wave = tid >> 6;          // 0..3
    const int lane = tid & 63;
    const int q    = lane >> 4;
    const int m    = lane & 15;
    const int b0   = (int)blockIdx.x * 16;

    // W_hh A-frags: lane holds W_hh[n = wave*64+tau*16+m][k = kap*32+q*8+0..7]
    // 32 frags = 128 regs/lane; launch_bounds(256,1) -> 512-reg budget (VGPR
    // or AGPR both fine: gfx950 MFMA reads A from AGPR natively).
    bf16x8 wf[4][8];
#pragma unroll
    for (int tau = 0; tau < 4; ++tau) {
        const float* wr = W_hh + (size_t)(wave * 64 + tau * 16 + m) * H_;
#pragma unroll
        for (int kap = 0; kap < 8; ++kap) {
            const int k0 = kap * 32 + q * 8;
            wf[tau][kap] = pack8(*(const float4*)(wr + k0), *(const float4*)(wr + k0 + 4));
        }
    }

    // LDS write indices (u16 units) for C -> B-frag relayout
    int widx[4];
#pragma unroll
    for (int tau = 0; tau < 4; ++tau) {
        const int nbw = wave * 64 + tau * 16 + q * 4;
        widx[tau] = (nbw >> 5) * 512 + (((nbw >> 3) & 3) * 16 + m) * 8 + (nbw & 7);
    }

    {   // zero h buffer 0 (8 KB = 512 uint4, 256 threads x2)
        uint4* p = (uint4*)&hbuf[0][0];
        const uint4 z = {0u, 0u, 0u, 0u};
        p[tid] = z; p[tid + 256] = z;
    }
    WG_BARRIER();

    // xw ([t][b][n]): lane reads 4 x uint2 per step at n = wave*64+tau*16+q*4.
    const u16* xwp = xw + (size_t)(b0 + m) * H_ + (wave * 64 + q * 4);
    const size_t tstride = (size_t)B_ * H_;

    uint2 pfA[4], pfB[4];                              // alternating, never copied
#pragma unroll
    for (int tau = 0; tau < 4; ++tau) {
        pfA[tau] = *(const uint2*)(xwp + tau * 16);
        pfB[tau] = *(const uint2*)(xwp + tstride + tau * 16);
    }

    int cur = 0;
    f32x4 acc[4];
    for (int tt = 0; tt < T_ / 2; ++tt) {
        // ---------- step A: t = 2*tt (even, never last) ----------
        {
            const int t = 2 * tt;
#pragma unroll
            for (int tau = 0; tau < 4; ++tau) acc[tau] = b4_to_f32x4(pfA[tau]);
            if (t + 2 < T_) {                          // reload pfA for t+2
                const u16* pt = xwp + (size_t)(t + 2) * tstride;
#pragma unroll
                for (int tau = 0; tau < 4; ++tau) pfA[tau] = *(const uint2*)(pt + tau * 16);
            }
            const uint4* hb = (const uint4*)&hbuf[cur][0];
#pragma unroll
            for (int kap = 0; kap < 8; ++kap) {        // 4 independent chains
                U16x8Cast c; c.v = hb[kap * 64 + lane];
#pragma unroll
                for (int tau = 0; tau < 4; ++tau)
                    acc[tau] = __builtin_amdgcn_mfma_f32_16x16x32_bf16(
                        wf[tau][kap], c.b, acc[tau], 0, 0, 0);
            }
            u16* wb = &hbuf[cur ^ 1][0];
#pragma unroll
            for (int tau = 0; tau < 4; ++tau) {
                uint2 pk = pack4(fast_tanh(acc[tau][0]), fast_tanh(acc[tau][1]),
                                 fast_tanh(acc[tau][2]), fast_tanh(acc[tau][3]));
                *(uint2*)(wb + widx[tau]) = pk;
            }
            WG_BARRIER();
            cur ^= 1;
        }
        // ---------- step B: t = 2*tt+1 (t = T_-1 on the last iter) ----------
        {
            const int t = 2 * tt + 1;
#pragma unroll
            for (int tau = 0; tau < 4; ++tau) acc[tau] = b4_to_f32x4(pfB[tau]);
            if (t + 2 < T_) {                          // reload pfB for t+2
                const u16* pt = xwp + (size_t)(t + 2) * tstride;
#pragma unroll
                for (int tau = 0; tau < 4; ++tau) pfB[tau] = *(const uint2*)(pt + tau * 16);
            }
            const uint4* hb = (const uint4*)&hbuf[cur][0];
#pragma unroll
            for (int kap = 0; kap < 8; ++kap) {
                U16x8Cast c; c.v = hb[kap * 64 + lane];
#pragma unroll
                for (int tau = 0; tau < 4; ++tau)
                    acc[tau] = __builtin_amdgcn_mfma_f32_16x16x32_bf16(
                        wf[tau][kap], c.b, acc[tau], 0, 0, 0);
            }
            if (t != T_ - 1) {                         // last h feeds fc only
                u16* wb = &hbuf[cur ^ 1][0];
#pragma unroll
                for (int tau = 0; tau < 4; ++tau) {
                    uint2 pk = pack4(fast_tanh(acc[tau][0]), fast_tanh(acc[tau][1]),
                                     fast_tanh(acc[tau][2]), fast_tanh(acc[tau][3]));
                    *(uint2*)(wb + widx[tau]) = pk;
                }
                WG_BARRIER();
                cur ^= 1;
            }
        }
    }

    // fc head: out[b] = sum_n tanh(h)[n] * fc_w[n] + fc_b
    float4 fcw[4];
#pragma unroll
    for (int tau = 0; tau < 4; ++tau)
        fcw[tau] = *(const float4*)(fc_w + wave * 64 + tau * 16 + q * 4);

    float partial = 0.f;
#pragma unroll
    for (int tau = 0; tau < 4; ++tau) {
        partial += fast_tanh(acc[tau][0]) * fcw[tau].x;
        partial += fast_tanh(acc[tau][1]) * fcw[tau].y;
        partial += fast_tanh(acc[tau][2]) * fcw[tau].z;
        partial += fast_tanh(acc[tau][3]) * fcw[tau].w;
    }
    partial += __shfl_xor(partial, 16);
    partial += __shfl_xor(partial, 32);
    __syncthreads();
    if (lane < 16) red[wave][m] = partial;
    __syncthreads();
    if (tid < 16)
        out[b0 + tid] = red[0][tid] + red[1][tid] + red[2][tid] + red[3][tid] + fc_b[0];
}

// =====================================================================
extern "C" void kernel_launch(void* const* d_in, const int* in_sizes, int n_in,
                              void* d_out, int out_size, void* d_ws, size_t ws_size,
                              hipStream_t stream) {
    const float* x    = (const float*)d_in[0];
    const float* W_ih = (const float*)d_in[1];
    const float* W_hh = (const float*)d_in[2];
    const float* b_ih = (const float*)d_in[3];
    const float* b_hh = (const float*)d_in[4];
    const float* fc_w = (const float*)d_in[5];
    const float* fc_b = (const float*)d_in[6];
    float* out = (float*)d_out;

    u16* xwbuf = (u16*)d_ws;                           // 64 MB bf16 [T][B][H]
    xw_gemm_mfma<<<(B_ * T_) / 128, 256, 0, stream>>>(x, W_ih, b_ih, b_hh, xwbuf);
    rnn_scan_mfma<<<B_ / 16, 256, 0, stream>>>(xwbuf, W_hh, fc_w, fc_b, out);
}